// Round 8
// baseline (652.434 us; speedup 1.0000x reference)
//
#include <hip/hip_runtime.h>
#include <hip/hip_bf16.h>

#define EPS 1e-5f

using bf16x8 = __attribute__((ext_vector_type(8))) short;
using f32x4  = __attribute__((ext_vector_type(4))) float;

// split f into bf16 hi (round-half-up) + bf16 lo(residual), as raw ushort bits
__device__ __forceinline__ void bf16_split(float f, unsigned short& h, unsigned short& l) {
    unsigned u = __float_as_uint(f);
    unsigned hu = (u + 0x8000u) & 0xFFFF0000u;
    float fh = __uint_as_float(hu);
    h = (unsigned short)(hu >> 16);
    float rl = f - fh;
    unsigned ul = __float_as_uint(rl);
    l = (unsigned short)((ul + 0x8000u) >> 16);
}

// ---------------------------------------------------------------- W prep
// split W1,W2 (row-major [k][n], 128x128 f32) into bf16 hi/lo, TRANSPOSED
// to [n][k] so MFMA B-fragments read 16B contiguous.
__global__ __launch_bounds__(256) void k_wprep(const float* __restrict__ W1,
                                               const float* __restrict__ W2,
                                               unsigned short* __restrict__ w1h,
                                               unsigned short* __restrict__ w1l,
                                               unsigned short* __restrict__ w2h,
                                               unsigned short* __restrict__ w2l) {
    int idx = blockIdx.x * 256 + threadIdx.x;           // 2*128*128 = 32768
    if (idx >= 32768) return;
    int mtx = idx >> 14;
    int rem = idx & 16383;
    int k = rem >> 7, n = rem & 127;
    float w = mtx ? W2[k * 128 + n] : W1[k * 128 + n];
    unsigned short h, l;
    bf16_split(w, h, l);
    if (mtx) { w2h[n * 128 + k] = h; w2l[n * 128 + k] = l; }
    else     { w1h[n * 128 + k] = h; w1l[n * 128 + k] = l; }
}

// ---------------------------------------------------------------- histogram + rank
__global__ __launch_bounds__(256) void k_histrank(const int* __restrict__ dst,
                                                  int* __restrict__ counts,
                                                  int* __restrict__ rank, int nE) {
    int i = blockIdx.x * 256 + threadIdx.x;
    if (i < nE) {
        int p = atomicAdd(&counts[dst[i]], 1);
        __builtin_nontemporal_store(p, &rank[i]);
    }
}

// ---------------------------------------------------------------- scan (3 phases)
__global__ __launch_bounds__(256) void k_scan1(const int* __restrict__ counts,
                                               int* __restrict__ bsums, int n) {
    __shared__ int sdata[256];
    int base = blockIdx.x * 2048;
    int t = threadIdx.x;
    int s = 0;
#pragma unroll
    for (int i = 0; i < 8; ++i) {
        int idx = base + t * 8 + i;
        if (idx < n) s += counts[idx];
    }
    sdata[t] = s;
    __syncthreads();
    for (int off = 128; off > 0; off >>= 1) {
        if (t < off) sdata[t] += sdata[t + off];
        __syncthreads();
    }
    if (t == 0) bsums[blockIdx.x] = sdata[0];
}

__global__ __launch_bounds__(64) void k_scan2(int* __restrict__ bsums, int nb) {
    if (threadIdx.x == 0 && blockIdx.x == 0) {
        int acc = 0;
        for (int i = 0; i < nb; ++i) { int v = bsums[i]; bsums[i] = acc; acc += v; }
    }
}

__global__ __launch_bounds__(256) void k_scan3(const int* __restrict__ counts,
                                               const int* __restrict__ bsums,
                                               int* __restrict__ rowstart,
                                               int n, int nE) {
    __shared__ int sth[256];
    int base = blockIdx.x * 2048;
    int t = threadIdx.x;
    int loc[8];
    int s = 0;
#pragma unroll
    for (int i = 0; i < 8; ++i) {
        int idx = base + t * 8 + i;
        loc[i] = s;
        s += (idx < n) ? counts[idx] : 0;
    }
    sth[t] = s;
    __syncthreads();
    for (int off = 1; off < 256; off <<= 1) {
        int tmp = (t >= off) ? sth[t - off] : 0;
        __syncthreads();
        sth[t] += tmp;
        __syncthreads();
    }
    int excl = sth[t] - s + bsums[blockIdx.x];
#pragma unroll
    for (int i = 0; i < 8; ++i) {
        int idx = base + t * 8 + i;
        if (idx < n) rowstart[idx] = excl + loc[i];
    }
    if (blockIdx.x == 0 && t == 0) rowstart[n] = nE;
}

// ---------------------------------------------------------------- CSR fill (no atomics)
__global__ __launch_bounds__(256) void k_fill3(const int* __restrict__ srci,
                                               const int* __restrict__ dsti,
                                               const int* __restrict__ rank,
                                               const int* __restrict__ rowstart,
                                               int* __restrict__ col, int nE) {
    int e = blockIdx.x * 256 + threadIdx.x;
    if (e < nE) {
        col[rowstart[dsti[e]] + rank[e]] = srci[e];
    }
}

// ---------------------------------------------------------------- linear via bf16-split MFMA
// out[64 rows x 128 cols] per block = X_tile @ W + bias, computed as
// xh@Wh + xh@Wl + xl@Wh (fp32 accum).  4 waves; wave w owns rows [16w,16w+16).
// mfma_f32_16x16x32_bf16 layouts (m89-verified):
//   A: row=lane&15, k=(lane>>4)*8+j    B: col=lane&15, k=(lane>>4)*8+j
//   D: col=lane&15, row=(lane>>4)*4+reg
__global__ __launch_bounds__(256) void k_linmf(const float* __restrict__ X,
                                               const unsigned short* __restrict__ WhT,
                                               const unsigned short* __restrict__ WlT,
                                               const float* __restrict__ bias,
                                               float* __restrict__ out, int nRows) {
    __shared__ __align__(16) unsigned short xh[64][136];
    __shared__ __align__(16) unsigned short xl[64][136];
    int row0 = blockIdx.x * 64;
    int tid = threadIdx.x;

    for (int i = tid; i < 64 * 32; i += 256) {
        int r = i >> 5, c4 = (i & 31) << 2;
        float4 v = make_float4(0.f, 0.f, 0.f, 0.f);
        int row = row0 + r;
        if (row < nRows) v = *(const float4*)(X + (size_t)row * 128 + c4);
        unsigned short h0, l0, h1, l1, h2, l2, h3, l3;
        bf16_split(v.x, h0, l0); bf16_split(v.y, h1, l1);
        bf16_split(v.z, h2, l2); bf16_split(v.w, h3, l3);
        xh[r][c4] = h0; xh[r][c4 + 1] = h1; xh[r][c4 + 2] = h2; xh[r][c4 + 3] = h3;
        xl[r][c4] = l0; xl[r][c4 + 1] = l1; xl[r][c4 + 2] = l2; xl[r][c4 + 3] = l3;
    }
    __syncthreads();

    int w = tid >> 6, lane = tid & 63;
    int t16 = lane & 15;          // A-row within tile / B-col within tile / D-col
    int kg = lane >> 4;           // k subgroup (8 elems each)

    f32x4 acc[8];
#pragma unroll
    for (int ct = 0; ct < 8; ++ct) acc[ct] = (f32x4){0.f, 0.f, 0.f, 0.f};

    for (int k0 = 0; k0 < 128; k0 += 32) {
        bf16x8 ah = *(const bf16x8*)&xh[w * 16 + t16][k0 + kg * 8];
        bf16x8 al = *(const bf16x8*)&xl[w * 16 + t16][k0 + kg * 8];
#pragma unroll
        for (int ct = 0; ct < 8; ++ct) {
            size_t boff = (size_t)(ct * 16 + t16) * 128 + k0 + kg * 8;
            bf16x8 bh = *(const bf16x8*)(WhT + boff);
            bf16x8 bl = *(const bf16x8*)(WlT + boff);
            acc[ct] = __builtin_amdgcn_mfma_f32_16x16x32_bf16(ah, bh, acc[ct], 0, 0, 0);
            acc[ct] = __builtin_amdgcn_mfma_f32_16x16x32_bf16(ah, bl, acc[ct], 0, 0, 0);
            acc[ct] = __builtin_amdgcn_mfma_f32_16x16x32_bf16(al, bh, acc[ct], 0, 0, 0);
        }
    }

#pragma unroll
    for (int ct = 0; ct < 8; ++ct) {
        int c = ct * 16 + t16;
        float b = bias[c];
#pragma unroll
        for (int j = 0; j < 4; ++j) {
            int r = row0 + w * 16 + kg * 4 + j;
            if (r < nRows) out[(size_t)r * 128 + c] = acc[ct][j] + b;
        }
    }
}

// ---------------------------------------------------------------- gather (float4 half-split)
template <bool FUSE_BN>
__global__ __launch_bounds__(256) void k_gather(const float* __restrict__ src,
                                                const int* __restrict__ rowstart,
                                                const int* __restrict__ col,
                                                const float* __restrict__ g,
                                                const float* __restrict__ be,
                                                const float* __restrict__ m,
                                                const float* __restrict__ v,
                                                float* __restrict__ out, int nRows) {
    int r = blockIdx.x * 4 + (threadIdx.x >> 6);
    if (r >= nRows) return;
    int lane = threadIdx.x & 63;
    int half = lane >> 5;
    int li = lane & 31;
    int d0 = li * 4;
    int s = rowstart[r], e = rowstart[r + 1];
    int deg = e - s;

    float4 acc = make_float4(0.f, 0.f, 0.f, 0.f);
    if (half == 0) acc = *(const float4*)(src + (size_t)r * 128 + d0);   // self loop

    int nP = deg >> 1;
    int p = 0;
    for (; p + 4 <= nP; p += 4) {
        int jb = s + 2 * p + half;
        int c0i = col[jb], c1i = col[jb + 2], c2i = col[jb + 4], c3i = col[jb + 6];
        float4 t0 = *(const float4*)(src + (size_t)c0i * 128 + d0);
        float4 t1 = *(const float4*)(src + (size_t)c1i * 128 + d0);
        float4 t2 = *(const float4*)(src + (size_t)c2i * 128 + d0);
        float4 t3 = *(const float4*)(src + (size_t)c3i * 128 + d0);
        acc.x += (t0.x + t1.x) + (t2.x + t3.x);
        acc.y += (t0.y + t1.y) + (t2.y + t3.y);
        acc.z += (t0.z + t1.z) + (t2.z + t3.z);
        acc.w += (t0.w + t1.w) + (t2.w + t3.w);
    }
    for (; p < nP; ++p) {
        int ci = col[s + 2 * p + half];
        float4 t = *(const float4*)(src + (size_t)ci * 128 + d0);
        acc.x += t.x; acc.y += t.y; acc.z += t.z; acc.w += t.w;
    }
    if ((deg & 1) && half == 0) {
        int ci = col[e - 1];
        float4 t = *(const float4*)(src + (size_t)ci * 128 + d0);
        acc.x += t.x; acc.y += t.y; acc.z += t.z; acc.w += t.w;
    }

    acc.x += __shfl_xor(acc.x, 32, 64);
    acc.y += __shfl_xor(acc.y, 32, 64);
    acc.z += __shfl_xor(acc.z, 32, 64);
    acc.w += __shfl_xor(acc.w, 32, 64);

    if (half == 0) {
        float rc = 1.0f / (float)(deg + 1);
        float4 o;
        if (FUSE_BN) {
            float4 gv  = *(const float4*)(g + d0);
            float4 bev = *(const float4*)(be + d0);
            float4 mv  = *(const float4*)(m + d0);
            float4 vv  = *(const float4*)(v + d0);
            o.x = fmaxf((acc.x * rc - mv.x) * rsqrtf(vv.x + EPS) * gv.x + bev.x, 0.f);
            o.y = fmaxf((acc.y * rc - mv.y) * rsqrtf(vv.y + EPS) * gv.y + bev.y, 0.f);
            o.z = fmaxf((acc.z * rc - mv.z) * rsqrtf(vv.z + EPS) * gv.z + bev.z, 0.f);
            o.w = fmaxf((acc.w * rc - mv.w) * rsqrtf(vv.w + EPS) * gv.w + bev.w, 0.f);
        } else {
            o.x = acc.x * rc; o.y = acc.y * rc; o.z = acc.z * rc; o.w = acc.w * rc;
        }
        *(float4*)(out + (size_t)r * 128 + d0) = o;
    }
}

// ---------------------------------------------------------------- final head
__global__ __launch_bounds__(256) void k_final(const float* __restrict__ xin,
                                               const float* __restrict__ Wc1,
                                               const float* __restrict__ bc1,
                                               const float* __restrict__ Wc2,
                                               const float* __restrict__ bc2,
                                               float* __restrict__ out, int nRows) {
    __shared__ float xs[32][132];
    __shared__ float w1s[128][64];
    __shared__ float hs[32][68];
    int row0 = blockIdx.x * 32;
    int tid = threadIdx.x;

    for (int i = tid; i < 2048; i += 256) {
        int kk = i >> 4, c4 = (i & 15) << 2;
        *(float4*)&w1s[kk][c4] = *(const float4*)(Wc1 + kk * 64 + c4);
    }
    for (int i = tid; i < 1024; i += 256) {
        int r = i >> 5, c4 = (i & 31) << 2;
        int row = row0 + r;
        float4 o = make_float4(0.f, 0.f, 0.f, 0.f);
        if (row < nRows) o = *(const float4*)(xin + (size_t)row * 128 + c4);
        *(float4*)&xs[r][c4] = o;
    }
    __syncthreads();

    int cg = tid & 15, rg = tid >> 4;
    int c0 = cg * 4, r0 = rg * 2;
    float acc[2][4];
    float4 bc = *(const float4*)(bc1 + c0);
    acc[0][0] = bc.x; acc[0][1] = bc.y; acc[0][2] = bc.z; acc[0][3] = bc.w;
    acc[1][0] = bc.x; acc[1][1] = bc.y; acc[1][2] = bc.z; acc[1][3] = bc.w;
    for (int k = 0; k < 128; ++k) {
        float4 w4 = *(const float4*)&w1s[k][c0];
        float x0 = xs[r0][k], x1 = xs[r0 + 1][k];
        acc[0][0] = fmaf(x0, w4.x, acc[0][0]);
        acc[0][1] = fmaf(x0, w4.y, acc[0][1]);
        acc[0][2] = fmaf(x0, w4.z, acc[0][2]);
        acc[0][3] = fmaf(x0, w4.w, acc[0][3]);
        acc[1][0] = fmaf(x1, w4.x, acc[1][0]);
        acc[1][1] = fmaf(x1, w4.y, acc[1][1]);
        acc[1][2] = fmaf(x1, w4.z, acc[1][2]);
        acc[1][3] = fmaf(x1, w4.w, acc[1][3]);
    }
    *(float4*)&hs[r0][c0] = make_float4(fmaxf(acc[0][0], 0.f), fmaxf(acc[0][1], 0.f),
                                        fmaxf(acc[0][2], 0.f), fmaxf(acc[0][3], 0.f));
    *(float4*)&hs[r0 + 1][c0] = make_float4(fmaxf(acc[1][0], 0.f), fmaxf(acc[1][1], 0.f),
                                            fmaxf(acc[1][2], 0.f), fmaxf(acc[1][3], 0.f));
    __syncthreads();

    if (tid < 64) {
        int r = tid >> 1, oc = tid & 1;
        float s = bc2[oc];
        for (int c = 0; c < 64; ++c) s = fmaf(hs[r][c], Wc2[c * 2 + oc], s);
        int row = row0 + r;
        if (row < nRows) out[(size_t)row * 2 + oc] = s;
    }
}

// ---------------------------------------------------------------- launch
extern "C" void kernel_launch(void* const* d_in, const int* in_sizes, int n_in,
                              void* d_out, int out_size, void* d_ws, size_t ws_size,
                              hipStream_t stream) {
    const float* x   = (const float*)d_in[0];
    const int*   ei  = (const int*)d_in[1];
    const float* W1  = (const float*)d_in[2];
    const float* b1  = (const float*)d_in[3];
    const float* g1  = (const float*)d_in[4];
    const float* be1 = (const float*)d_in[5];
    const float* m1  = (const float*)d_in[6];
    const float* v1  = (const float*)d_in[7];
    const float* W2  = (const float*)d_in[8];
    const float* b2  = (const float*)d_in[9];
    const float* g2  = (const float*)d_in[10];
    const float* be2 = (const float*)d_in[11];
    const float* m2  = (const float*)d_in[12];
    const float* v2  = (const float*)d_in[13];
    const float* Wc1 = (const float*)d_in[14];
    const float* bc1 = (const float*)d_in[15];
    const float* Wc2 = (const float*)d_in[16];
    const float* bc2 = (const float*)d_in[17];

    const int N_ = in_sizes[0] / 128;
    const int E_ = in_sizes[1] / 2;
    const int* srci = ei;
    const int* dsti = ei + E_;

    float* A = (float*)d_ws;                       // [N,128]
    float* B = A + (size_t)N_ * 128;               // [N,128]; rank aliases B
    int* rank = (int*)B;                           // [E] int, dead before gather-1
    int* counts   = (int*)(B + (size_t)N_ * 128);  // N
    int* rowstart = counts + N_;                   // N+1
    int* bsums    = rowstart + N_ + 1;             // 256
    int* col      = bsums + 256;                   // E
    uintptr_t wp  = ((uintptr_t)(col + E_) + 63) & ~(uintptr_t)63;
    unsigned short* w1h = (unsigned short*)wp;     // 4x [128][128] bf16 (32KB each)
    unsigned short* w1l = w1h + 16384;
    unsigned short* w2h = w1l + 16384;
    unsigned short* w2l = w2h + 16384;

    const int nb = (N_ + 2047) / 2048;

    // ---- W split/transpose prep (tiny)
    k_wprep<<<128, 256, 0, stream>>>(W1, W2, w1h, w1l, w2h, w2l);

    // ---- CSR build (rank trick: single atomic pass, atomic-free fill)
    hipMemsetAsync(counts, 0, (size_t)N_ * sizeof(int), stream);
    k_histrank<<<(E_ + 255) / 256, 256, 0, stream>>>(dsti, counts, rank, E_);
    k_scan1   <<<nb, 256, 0, stream>>>(counts, bsums, N_);
    k_scan2   <<<1, 64, 0, stream>>>(bsums, nb);
    k_scan3   <<<nb, 256, 0, stream>>>(counts, bsums, rowstart, N_, E_);
    k_fill3   <<<(E_ + 255) / 256, 256, 0, stream>>>(srci, dsti, rank, rowstart,
                                                     col, E_);

    // ---- layer 1
    k_linmf<<<(N_ + 63) / 64, 256, 0, stream>>>(x, w1h, w1l, b1, A, N_);
    k_gather<true><<<(N_ + 3) / 4, 256, 0, stream>>>(A, rowstart, col,
                                                     g1, be1, m1, v1, B, N_);

    // ---- layer 2
    k_linmf<<<(N_ + 63) / 64, 256, 0, stream>>>(B, w2h, w2l, b2, A, N_);
    k_gather<true><<<(N_ + 3) / 4, 256, 0, stream>>>(A, rowstart, col,
                                                     g2, be2, m2, v2, B, N_);

    // ---- MLP head
    k_final<<<(N_ + 31) / 32, 256, 0, stream>>>(B, Wc1, bc1, Wc2, bc2,
                                                (float*)d_out, N_);
}

// Round 9
// 634.209 us; speedup vs baseline: 1.0287x; 1.0287x over previous
//
#include <hip/hip_runtime.h>
#include <hip/hip_bf16.h>

#define EPS 1e-5f

using bf16x8 = __attribute__((ext_vector_type(8))) short;
using f32x4  = __attribute__((ext_vector_type(4))) float;

// split f into bf16 hi (round-half-up) + bf16 lo(residual), as raw ushort bits
__device__ __forceinline__ void bf16_split(float f, unsigned short& h, unsigned short& l) {
    unsigned u = __float_as_uint(f);
    unsigned hu = (u + 0x8000u) & 0xFFFF0000u;
    float fh = __uint_as_float(hu);
    h = (unsigned short)(hu >> 16);
    float rl = f - fh;
    unsigned ul = __float_as_uint(rl);
    l = (unsigned short)((ul + 0x8000u) >> 16);
}

// ---------------------------------------------------------------- W prep
// split W1,W2 (row-major [k][n], 128x128 f32) into bf16 hi/lo, TRANSPOSED
// to [n][k] so MFMA B-fragments read 16B contiguous.
__global__ __launch_bounds__(256) void k_wprep(const float* __restrict__ W1,
                                               const float* __restrict__ W2,
                                               unsigned short* __restrict__ w1h,
                                               unsigned short* __restrict__ w1l,
                                               unsigned short* __restrict__ w2h,
                                               unsigned short* __restrict__ w2l) {
    int idx = blockIdx.x * 256 + threadIdx.x;           // 2*128*128 = 32768
    if (idx >= 32768) return;
    int mtx = idx >> 14;
    int rem = idx & 16383;
    int k = rem >> 7, n = rem & 127;
    float w = mtx ? W2[k * 128 + n] : W1[k * 128 + n];
    unsigned short h, l;
    bf16_split(w, h, l);
    if (mtx) { w2h[n * 128 + k] = h; w2l[n * 128 + k] = l; }
    else     { w1h[n * 128 + k] = h; w1l[n * 128 + k] = l; }
}

// ---------------------------------------------------------------- histogram + rank
__global__ __launch_bounds__(256) void k_histrank(const int* __restrict__ dst,
                                                  int* __restrict__ counts,
                                                  int* __restrict__ rank, int nE) {
    int i = blockIdx.x * 256 + threadIdx.x;
    if (i < nE) {
        int p = atomicAdd(&counts[dst[i]], 1);
        __builtin_nontemporal_store(p, &rank[i]);
    }
}

// ---------------------------------------------------------------- scan (3 phases)
__global__ __launch_bounds__(256) void k_scan1(const int* __restrict__ counts,
                                               int* __restrict__ bsums, int n) {
    __shared__ int sdata[256];
    int base = blockIdx.x * 2048;
    int t = threadIdx.x;
    int s = 0;
#pragma unroll
    for (int i = 0; i < 8; ++i) {
        int idx = base + t * 8 + i;
        if (idx < n) s += counts[idx];
    }
    sdata[t] = s;
    __syncthreads();
    for (int off = 128; off > 0; off >>= 1) {
        if (t < off) sdata[t] += sdata[t + off];
        __syncthreads();
    }
    if (t == 0) bsums[blockIdx.x] = sdata[0];
}

__global__ __launch_bounds__(64) void k_scan2(int* __restrict__ bsums, int nb) {
    if (threadIdx.x == 0 && blockIdx.x == 0) {
        int acc = 0;
        for (int i = 0; i < nb; ++i) { int v = bsums[i]; bsums[i] = acc; acc += v; }
    }
}

__global__ __launch_bounds__(256) void k_scan3(const int* __restrict__ counts,
                                               const int* __restrict__ bsums,
                                               int* __restrict__ rowstart,
                                               int n, int nE) {
    __shared__ int sth[256];
    int base = blockIdx.x * 2048;
    int t = threadIdx.x;
    int loc[8];
    int s = 0;
#pragma unroll
    for (int i = 0; i < 8; ++i) {
        int idx = base + t * 8 + i;
        loc[i] = s;
        s += (idx < n) ? counts[idx] : 0;
    }
    sth[t] = s;
    __syncthreads();
    for (int off = 1; off < 256; off <<= 1) {
        int tmp = (t >= off) ? sth[t - off] : 0;
        __syncthreads();
        sth[t] += tmp;
        __syncthreads();
    }
    int excl = sth[t] - s + bsums[blockIdx.x];
#pragma unroll
    for (int i = 0; i < 8; ++i) {
        int idx = base + t * 8 + i;
        if (idx < n) rowstart[idx] = excl + loc[i];
    }
    if (blockIdx.x == 0 && t == 0) rowstart[n] = nE;
}

// ---------------------------------------------------------------- CSR fill (no atomics)
__global__ __launch_bounds__(256) void k_fill3(const int* __restrict__ srci,
                                               const int* __restrict__ dsti,
                                               const int* __restrict__ rank,
                                               const int* __restrict__ rowstart,
                                               int* __restrict__ col, int nE) {
    int e = blockIdx.x * 256 + threadIdx.x;
    if (e < nE) {
        col[rowstart[dsti[e]] + rank[e]] = srci[e];
    }
}

// ---------------------------------------------------------------- gather (mean only)
// one wave per dst row; float4 half-split (round-7 verified).
__global__ __launch_bounds__(256) void k_gather(const float* __restrict__ src,
                                                const int* __restrict__ rowstart,
                                                const int* __restrict__ col,
                                                float* __restrict__ out, int nRows) {
    int r = blockIdx.x * 4 + (threadIdx.x >> 6);
    if (r >= nRows) return;
    int lane = threadIdx.x & 63;
    int half = lane >> 5;
    int li = lane & 31;
    int d0 = li * 4;
    int s = rowstart[r], e = rowstart[r + 1];
    int deg = e - s;

    float4 acc = make_float4(0.f, 0.f, 0.f, 0.f);
    if (half == 0) acc = *(const float4*)(src + (size_t)r * 128 + d0);   // self loop

    int nP = deg >> 1;
    int p = 0;
    for (; p + 4 <= nP; p += 4) {
        int jb = s + 2 * p + half;
        int c0i = col[jb], c1i = col[jb + 2], c2i = col[jb + 4], c3i = col[jb + 6];
        float4 t0 = *(const float4*)(src + (size_t)c0i * 128 + d0);
        float4 t1 = *(const float4*)(src + (size_t)c1i * 128 + d0);
        float4 t2 = *(const float4*)(src + (size_t)c2i * 128 + d0);
        float4 t3 = *(const float4*)(src + (size_t)c3i * 128 + d0);
        acc.x += (t0.x + t1.x) + (t2.x + t3.x);
        acc.y += (t0.y + t1.y) + (t2.y + t3.y);
        acc.z += (t0.z + t1.z) + (t2.z + t3.z);
        acc.w += (t0.w + t1.w) + (t2.w + t3.w);
    }
    for (; p < nP; ++p) {
        int ci = col[s + 2 * p + half];
        float4 t = *(const float4*)(src + (size_t)ci * 128 + d0);
        acc.x += t.x; acc.y += t.y; acc.z += t.z; acc.w += t.w;
    }
    if ((deg & 1) && half == 0) {
        int ci = col[e - 1];
        float4 t = *(const float4*)(src + (size_t)ci * 128 + d0);
        acc.x += t.x; acc.y += t.y; acc.z += t.z; acc.w += t.w;
    }

    acc.x += __shfl_xor(acc.x, 32, 64);
    acc.y += __shfl_xor(acc.y, 32, 64);
    acc.z += __shfl_xor(acc.z, 32, 64);
    acc.w += __shfl_xor(acc.w, 32, 64);

    if (half == 0) {
        float rc = 1.0f / (float)(deg + 1);
        float4 o = make_float4(acc.x * rc, acc.y * rc, acc.z * rc, acc.w * rc);
        *(float4*)(out + (size_t)r * 128 + d0) = o;
    }
}

// ---------------------------------------------------------------- lin + BN + ReLU (MFMA)
// out = relu(bn(X @ W + bias)) for a 64-row tile.  X = aggregated means.
// xh@Wh + xh@Wl + xl@Wh bf16-split MFMA (round-8 verified layouts).
__global__ __launch_bounds__(256) void k_lin_bn(const float* __restrict__ X,
                                                const unsigned short* __restrict__ WhT,
                                                const unsigned short* __restrict__ WlT,
                                                const float* __restrict__ bias,
                                                const float* __restrict__ g,
                                                const float* __restrict__ be,
                                                const float* __restrict__ m,
                                                const float* __restrict__ v,
                                                float* __restrict__ out, int nRows) {
    __shared__ __align__(16) unsigned short xh[64][136];
    __shared__ __align__(16) unsigned short xl[64][136];
    int row0 = blockIdx.x * 64;
    int tid = threadIdx.x;

    for (int i = tid; i < 64 * 32; i += 256) {
        int r = i >> 5, c4 = (i & 31) << 2;
        float4 vv = make_float4(0.f, 0.f, 0.f, 0.f);
        int row = row0 + r;
        if (row < nRows) vv = *(const float4*)(X + (size_t)row * 128 + c4);
        unsigned short h0, l0, h1, l1, h2, l2, h3, l3;
        bf16_split(vv.x, h0, l0); bf16_split(vv.y, h1, l1);
        bf16_split(vv.z, h2, l2); bf16_split(vv.w, h3, l3);
        xh[r][c4] = h0; xh[r][c4 + 1] = h1; xh[r][c4 + 2] = h2; xh[r][c4 + 3] = h3;
        xl[r][c4] = l0; xl[r][c4 + 1] = l1; xl[r][c4 + 2] = l2; xl[r][c4 + 3] = l3;
    }
    __syncthreads();

    int w = tid >> 6, lane = tid & 63;
    int t16 = lane & 15;
    int kg = lane >> 4;

    f32x4 acc[8];
#pragma unroll
    for (int ct = 0; ct < 8; ++ct) acc[ct] = (f32x4){0.f, 0.f, 0.f, 0.f};

    for (int k0 = 0; k0 < 128; k0 += 32) {
        bf16x8 ah = *(const bf16x8*)&xh[w * 16 + t16][k0 + kg * 8];
        bf16x8 al = *(const bf16x8*)&xl[w * 16 + t16][k0 + kg * 8];
#pragma unroll
        for (int ct = 0; ct < 8; ++ct) {
            size_t boff = (size_t)(ct * 16 + t16) * 128 + k0 + kg * 8;
            bf16x8 bh = *(const bf16x8*)(WhT + boff);
            bf16x8 bl = *(const bf16x8*)(WlT + boff);
            acc[ct] = __builtin_amdgcn_mfma_f32_16x16x32_bf16(ah, bh, acc[ct], 0, 0, 0);
            acc[ct] = __builtin_amdgcn_mfma_f32_16x16x32_bf16(ah, bl, acc[ct], 0, 0, 0);
            acc[ct] = __builtin_amdgcn_mfma_f32_16x16x32_bf16(al, bh, acc[ct], 0, 0, 0);
        }
    }

#pragma unroll
    for (int ct = 0; ct < 8; ++ct) {
        int c = ct * 16 + t16;
        float sc = rsqrtf(v[c] + EPS) * g[c];
        float sh = be[c] - m[c] * sc;
        float bb = bias[c];
#pragma unroll
        for (int j = 0; j < 4; ++j) {
            int r = row0 + w * 16 + kg * 4 + j;
            if (r < nRows)
                out[(size_t)r * 128 + c] = fmaxf((acc[ct][j] + bb) * sc + sh, 0.f);
        }
    }
}

// ---------------------------------------------------------------- lin + BN + ReLU + MLP head
// tile = relu(bn2(X @ W2 + b2)) -> LDS; hid = relu(tile@Wc1+bc1); out = hid@Wc2+bc2
// Wc1 (32KB) read from global (L1/L2-resident). 64-row blocks, 256 threads.
__global__ __launch_bounds__(256) void k_lin2_head(const float* __restrict__ X,
                                                   const unsigned short* __restrict__ WhT,
                                                   const unsigned short* __restrict__ WlT,
                                                   const float* __restrict__ bias,
                                                   const float* __restrict__ g,
                                                   const float* __restrict__ be,
                                                   const float* __restrict__ m,
                                                   const float* __restrict__ v,
                                                   const float* __restrict__ Wc1,
                                                   const float* __restrict__ bc1,
                                                   const float* __restrict__ Wc2,
                                                   const float* __restrict__ bc2,
                                                   float* __restrict__ out, int nRows) {
    __shared__ __align__(16) char smem[64 * 136 * 2 * 2];     // 34816 B
    __shared__ float hs[64][68];                              // 17408 B
    unsigned short (*xh)[136] = (unsigned short (*)[136])smem;
    unsigned short (*xl)[136] = (unsigned short (*)[136])(smem + 64 * 136 * 2);
    float (*xs)[132] = (float (*)[132])smem;                  // aliases xh/xl after MFMA

    int row0 = blockIdx.x * 64;
    int tid = threadIdx.x;

    for (int i = tid; i < 64 * 32; i += 256) {
        int r = i >> 5, c4 = (i & 31) << 2;
        float4 vv = make_float4(0.f, 0.f, 0.f, 0.f);
        int row = row0 + r;
        if (row < nRows) vv = *(const float4*)(X + (size_t)row * 128 + c4);
        unsigned short h0, l0, h1, l1, h2, l2, h3, l3;
        bf16_split(vv.x, h0, l0); bf16_split(vv.y, h1, l1);
        bf16_split(vv.z, h2, l2); bf16_split(vv.w, h3, l3);
        xh[r][c4] = h0; xh[r][c4 + 1] = h1; xh[r][c4 + 2] = h2; xh[r][c4 + 3] = h3;
        xl[r][c4] = l0; xl[r][c4 + 1] = l1; xl[r][c4 + 2] = l2; xl[r][c4 + 3] = l3;
    }
    __syncthreads();

    int w = tid >> 6, lane = tid & 63;
    int t16 = lane & 15;
    int kg = lane >> 4;

    f32x4 acc[8];
#pragma unroll
    for (int ct = 0; ct < 8; ++ct) acc[ct] = (f32x4){0.f, 0.f, 0.f, 0.f};

    for (int k0 = 0; k0 < 128; k0 += 32) {
        bf16x8 ah = *(const bf16x8*)&xh[w * 16 + t16][k0 + kg * 8];
        bf16x8 al = *(const bf16x8*)&xl[w * 16 + t16][k0 + kg * 8];
#pragma unroll
        for (int ct = 0; ct < 8; ++ct) {
            size_t boff = (size_t)(ct * 16 + t16) * 128 + k0 + kg * 8;
            bf16x8 bh = *(const bf16x8*)(WhT + boff);
            bf16x8 bl = *(const bf16x8*)(WlT + boff);
            acc[ct] = __builtin_amdgcn_mfma_f32_16x16x32_bf16(ah, bh, acc[ct], 0, 0, 0);
            acc[ct] = __builtin_amdgcn_mfma_f32_16x16x32_bf16(ah, bl, acc[ct], 0, 0, 0);
            acc[ct] = __builtin_amdgcn_mfma_f32_16x16x32_bf16(al, bh, acc[ct], 0, 0, 0);
        }
    }
    __syncthreads();   // all MFMA LDS reads done; xh/xl region now reusable as xs

    // bn2 + relu -> xs (LDS, fp32)
#pragma unroll
    for (int ct = 0; ct < 8; ++ct) {
        int c = ct * 16 + t16;
        float sc = rsqrtf(v[c] + EPS) * g[c];
        float sh = be[c] - m[c] * sc;
        float bb = bias[c];
#pragma unroll
        for (int j = 0; j < 4; ++j) {
            int lr = w * 16 + kg * 4 + j;
            xs[lr][c] = fmaxf((acc[ct][j] + bb) * sc + sh, 0.f);
        }
    }
    __syncthreads();

    // hid = relu(xs @ Wc1 + bc1): 64x64; thread = 4 rows x 4 cols
    {
        int cg = tid & 15, rg = tid >> 4;
        int c0 = cg * 4, r0 = rg * 4;
        float a2[4][4];
        float4 bc = *(const float4*)(bc1 + c0);
#pragma unroll
        for (int i = 0; i < 4; ++i) {
            a2[i][0] = bc.x; a2[i][1] = bc.y; a2[i][2] = bc.z; a2[i][3] = bc.w;
        }
        for (int k = 0; k < 128; ++k) {
            float4 w4 = *(const float4*)(Wc1 + k * 64 + c0);
#pragma unroll
            for (int i = 0; i < 4; ++i) {
                float xk = xs[r0 + i][k];
                a2[i][0] = fmaf(xk, w4.x, a2[i][0]);
                a2[i][1] = fmaf(xk, w4.y, a2[i][1]);
                a2[i][2] = fmaf(xk, w4.z, a2[i][2]);
                a2[i][3] = fmaf(xk, w4.w, a2[i][3]);
            }
        }
#pragma unroll
        for (int i = 0; i < 4; ++i) {
            *(float4*)&hs[r0 + i][c0] =
                make_float4(fmaxf(a2[i][0], 0.f), fmaxf(a2[i][1], 0.f),
                            fmaxf(a2[i][2], 0.f), fmaxf(a2[i][3], 0.f));
        }
    }
    __syncthreads();

    // logits: 64 rows x 2
    if (tid < 128) {
        int r = tid >> 1, oc = tid & 1;
        float s = bc2[oc];
        for (int c = 0; c < 64; ++c) s = fmaf(hs[r][c], Wc2[c * 2 + oc], s);
        int row = row0 + r;
        if (row < nRows) out[(size_t)row * 2 + oc] = s;
    }
}

// ---------------------------------------------------------------- launch
extern "C" void kernel_launch(void* const* d_in, const int* in_sizes, int n_in,
                              void* d_out, int out_size, void* d_ws, size_t ws_size,
                              hipStream_t stream) {
    const float* x   = (const float*)d_in[0];
    const int*   ei  = (const int*)d_in[1];
    const float* W1  = (const float*)d_in[2];
    const float* b1  = (const float*)d_in[3];
    const float* g1  = (const float*)d_in[4];
    const float* be1 = (const float*)d_in[5];
    const float* m1  = (const float*)d_in[6];
    const float* v1  = (const float*)d_in[7];
    const float* W2  = (const float*)d_in[8];
    const float* b2  = (const float*)d_in[9];
    const float* g2  = (const float*)d_in[10];
    const float* be2 = (const float*)d_in[11];
    const float* m2  = (const float*)d_in[12];
    const float* v2  = (const float*)d_in[13];
    const float* Wc1 = (const float*)d_in[14];
    const float* bc1 = (const float*)d_in[15];
    const float* Wc2 = (const float*)d_in[16];
    const float* bc2 = (const float*)d_in[17];

    const int N_ = in_sizes[0] / 128;
    const int E_ = in_sizes[1] / 2;
    const int* srci = ei;
    const int* dsti = ei + E_;

    float* A = (float*)d_ws;                       // [N,128] aggregate buffer
    float* B = A + (size_t)N_ * 128;               // [N,128]; rank aliases B
    int* rank = (int*)B;                           // [E] int, dead after fill3
    int* counts   = (int*)(B + (size_t)N_ * 128);  // N
    int* rowstart = counts + N_;                   // N+1
    int* bsums    = rowstart + N_ + 1;             // 256
    int* col      = bsums + 256;                   // E
    uintptr_t wp  = ((uintptr_t)(col + E_) + 63) & ~(uintptr_t)63;
    unsigned short* w1h = (unsigned short*)wp;     // 4x [128][128] bf16
    unsigned short* w1l = w1h + 16384;
    unsigned short* w2h = w1l + 16384;
    unsigned short* w2l = w2h + 16384;

    const int nb = (N_ + 2047) / 2048;

    // ---- W split/transpose prep (tiny)
    k_wprep<<<128, 256, 0, stream>>>(W1, W2, w1h, w1l, w2h, w2l);

    // ---- CSR build (rank trick: single atomic pass, atomic-free fill)
    hipMemsetAsync(counts, 0, (size_t)N_ * sizeof(int), stream);
    k_histrank<<<(E_ + 255) / 256, 256, 0, stream>>>(dsti, counts, rank, E_);
    k_scan1   <<<nb, 256, 0, stream>>>(counts, bsums, N_);
    k_scan2   <<<1, 64, 0, stream>>>(bsums, nb);
    k_scan3   <<<nb, 256, 0, stream>>>(counts, bsums, rowstart, N_, E_);
    k_fill3   <<<(E_ + 255) / 256, 256, 0, stream>>>(srci, dsti, rank, rowstart,
                                                     col, E_);

    // ---- layer 1: agg(x) -> A ; B = relu(bn1(A@W1+b1))
    k_gather<<<(N_ + 3) / 4, 256, 0, stream>>>(x, rowstart, col, A, N_);
    k_lin_bn<<<(N_ + 63) / 64, 256, 0, stream>>>(A, w1h, w1l, b1,
                                                 g1, be1, m1, v1, B, N_);

    // ---- layer 2 + head: agg(B) -> A ; out = head(relu(bn2(A@W2+b2)))
    k_gather<<<(N_ + 3) / 4, 256, 0, stream>>>(B, rowstart, col, A, N_);
    k_lin2_head<<<(N_ + 63) / 64, 256, 0, stream>>>(A, w2h, w2l, b2,
                                                    g2, be2, m2, v2,
                                                    Wc1, bc1, Wc2, bc2,
                                                    (float*)d_out, N_);
}